// Round 2
// baseline (106.113 us; speedup 1.0000x reference)
//
#include <hip/hip_runtime.h>
#include <math.h>

#define PI_F 3.14159265358979323846f

struct c32 { float x, y; };

// ---- 4-qubit state: 16 amps, wire w = bit (3-w) of index ----

// Rot gate in SU(2)-reduced form: matrix [[A, -conj(C)],[C, conj(A)]]
__device__ __forceinline__ void apply_rot_red(c32* s, const int w,
                                              float Ax, float Ay, float Cx, float Cy){
  const int m = 8 >> w;
  #pragma unroll
  for (int i = 0; i < 16; i++){
    if (i & m) continue;
    c32 a = s[i], b = s[i | m];
    s[i].x     = Ax*a.x - Ay*a.y - Cx*b.x - Cy*b.y;
    s[i].y     = Ax*a.y + Ay*a.x - Cx*b.y + Cy*b.x;
    s[i | m].x = Cx*a.x - Cy*a.y + Ax*b.x + Ay*b.y;
    s[i | m].y = Cx*a.y + Cy*a.x + Ax*b.y - Ay*b.x;
  }
}

// fused CRX(t) followed by CNOT on (control wa, target wb)
__device__ __forceinline__ void apply_crxnot(c32* s, const int wa, const int wb,
                                             float c, float sn){
  const int ma = 8 >> wa, mb = 8 >> wb;
  #pragma unroll
  for (int i = 0; i < 16; i++){
    if (!(i & ma) || (i & mb)) continue;
    c32 u = s[i], v = s[i | mb];
    s[i]      = { c*v.x + sn*u.y, c*v.y - sn*u.x };   // CNOT swap folded in
    s[i | mb] = { c*u.x + sn*v.y, c*u.y - sn*v.x };
  }
}

// gp: 8 gates x 8 floats {A.x,A.y,C.x,C.y,crx_c,crx_s,0,0}
__device__ __forceinline__ void sim_initqkv(c32* s, const float* __restrict__ gp){
  constexpr int pa[8] = {0,1,2,3,0,1,2,3};
  constexpr int pb[8] = {1,2,3,0,3,0,1,2};
  #pragma unroll
  for (int g = 0; g < 8; g++){
    const float* q = gp + 8*g;
    apply_rot_red(s, pa[g], q[0], q[1], q[2], q[3]);
    apply_crxnot(s, pa[g], pb[g], q[4], q[5]);
  }
}

// RX(x)|0000> is a product state: amp[i] = (prod of c/s) * (-i)^popcount(i)
__device__ __forceinline__ void build_rx(c32* s, const float* cw, const float* sw){
  float m01[4] = { cw[0]*cw[1], cw[0]*sw[1], sw[0]*cw[1], sw[0]*sw[1] };
  float m23[4] = { cw[2]*cw[3], cw[2]*sw[3], sw[2]*cw[3], sw[2]*sw[3] };
  #pragma unroll
  for (int i = 0; i < 16; i++){
    float mag = m01[(i >> 2) & 3] * m23[i & 3];
    const int pc = __popc(i) & 3;
    s[i] = (pc == 0) ? c32{ mag, 0.f } :
           (pc == 1) ? c32{ 0.f, -mag } :
           (pc == 2) ? c32{ -mag, 0.f } : c32{ 0.f, mag };
  }
}

__device__ __forceinline__ float fast_tanh(float x){
  float e = __expf(2.f * x);
  return 1.f - 2.f * __builtin_amdgcn_rcpf(e + 1.f);
}

// ================= setup: precompute gate matrices + k-circuit constants =================
// ws layout (floats): [0..63] q gates, [64..127] v gates, [128..131] cxk
__global__ __launch_bounds__(64) void qc_setup(
    const float* __restrict__ q_rot, const float* __restrict__ k_rot, const float* __restrict__ v_rot,
    const float* __restrict__ q_crx, const float* __restrict__ k_crx, const float* __restrict__ v_crx,
    float* __restrict__ ws){
  __shared__ float kg[64];
  const int t = threadIdx.x;
  if (t < 24){
    const int grp = t >> 3, g = t & 7;
    const float* rotp = grp == 0 ? q_rot : (grp == 1 ? k_rot : v_rot);
    const float* crxp = grp == 0 ? q_crx : (grp == 1 ? k_crx : v_crx);
    float phi = rotp[3*g], th = rotp[3*g+1], om = rotp[3*g+2];
    float c, s, ca, sa, cb, sb;
    __sincosf(0.5f*th,       &s,  &c);
    __sincosf(0.5f*(phi+om), &sa, &ca);
    __sincosf(0.5f*(phi-om), &sb, &cb);
    float cc, cs; __sincosf(0.5f*crxp[g], &cs, &cc);
    float vals[6] = { c*ca, -c*sa, s*cb, -s*sb, cc, cs };
    if (grp == 1){
      #pragma unroll
      for (int j = 0; j < 6; j++) kg[8*g + j] = vals[j];
    } else {
      float* dst = ws + (grp == 0 ? 0 : 64) + 8*g;
      #pragma unroll
      for (int j = 0; j < 6; j++) dst[j] = vals[j];
      dst[6] = 0.f; dst[7] = 0.f;
    }
  }
  __syncthreads();
  // k-circuit on |0000>: all threads compute (uniform), thread 0 writes expX constants
  c32 st[16];
  #pragma unroll
  for (int i = 0; i < 16; i++) st[i] = { 0.f, 0.f };
  st[0] = { 1.f, 0.f };
  sim_initqkv(st, kg);
  if (t == 0){
    #pragma unroll
    for (int w = 0; w < 4; w++){
      const int m = 8 >> w;
      float r = 0.f;
      #pragma unroll
      for (int i = 0; i < 16; i++){
        if (i & m) continue;
        r += st[i].x*st[i|m].x + st[i].y*st[i|m].y;
      }
      ws[128 + w] = 2.f * r;
    }
  }
}

// ================= main =================
#define LDS_STRIDE 97   // 97 % 32 == 1 -> only 2-way bank aliasing (free)

__global__ __launch_bounds__(64, 1) void qc_main(
    const float* __restrict__ x1,
    const float* __restrict__ pre_w, const float* __restrict__ pre_b,
    const float* __restrict__ ln_w, const float* __restrict__ ln_b,
    const float* __restrict__ head_w, const float* __restrict__ head_b,
    const float* __restrict__ ws,
    float* __restrict__ out, int B){

  __shared__ float xs[64 * LDS_STRIDE];
  const int t = threadIdx.x;
  const int base = blockIdx.x * 64;

  // stage 64x96 slice of x1 (coalesced float4)
  {
    int rem = B - base; if (rem > 64) rem = 64;
    const int nf4 = rem * 24;
    const float4* src = (const float4*)(x1 + (long)base * 96);
    #pragma unroll
    for (int k = 0; k < 24; k++){
      int g = t + 64*k;
      if (g < nf4){
        float4 v = src[g];
        int f = 4*g;
        int r = f / 96, cidx = f - 96*r;
        float* d = &xs[r*LDS_STRIDE + cidx];
        d[0]=v.x; d[1]=v.y; d[2]=v.z; d[3]=v.w;
      }
    }
  }
  __syncthreads();

  // x = row @ pre_w.T + pre_b (pre_w uniform -> scalar loads)
  float xw[4];
  {
    float a0 = pre_b[0], a1 = pre_b[1], a2 = pre_b[2], a3 = pre_b[3];
    const float* row = &xs[t * LDS_STRIDE];
    #pragma unroll
    for (int j = 0; j < 96; j++){
      float v = row[j];
      a0 += v * pre_w[j];
      a1 += v * pre_w[96  + j];
      a2 += v * pre_w[192 + j];
      a3 += v * pre_w[288 + j];
    }
    xw[0]=a0; xw[1]=a1; xw[2]=a2; xw[3]=a3;
  }

  float cw[4], sw[4];
  #pragma unroll
  for (int w = 0; w < 4; w++) __sincosf(0.5f*xw[w], &sw[w], &cw[w]);

  c32 st[16];

  // ---- q-circuit: phi = U_q RX(x)|0>; post-RX layer folded into expectations ----
  float cr[4], sr[4];   // half-angle cos/sin of RZ angles for v-circuit
  {
    build_rx(st, cw, sw);
    sim_initqkv(st, ws);           // q gates
    float p[16];
    #pragma unroll
    for (int i = 0; i < 16; i++) p[i] = st[i].x*st[i].x + st[i].y*st[i].y;
    #pragma unroll
    for (int w = 0; w < 4; w++){
      const int m = 8 >> w;
      float sz = 0.f, sx = 0.f, sy = 0.f;
      #pragma unroll
      for (int i = 0; i < 16; i++) sz += (i & m) ? -p[i] : p[i];
      #pragma unroll
      for (int i = 0; i < 16; i++){
        if (i & m) continue;
        c32 a = st[i], b = st[i|m];
        sx += a.x*b.x + a.y*b.y;
        sy += a.x*b.y - a.y*b.x;
      }
      // RX(theta)^dag Z RX(theta) = cos(th) Z + sin(th) Y ; X invariant
      float cth = 1.f - 2.f*sw[w]*sw[w];
      float sth = 2.f*sw[w]*cw[w];
      float z   = cth*sz + sth*(2.f*sy);
      float xm  = (2.f*sx) * ws[128 + w];     // * expX of k-circuit (uniform)
      float score = sqrtf(z*z + xm*xm);
      float th = fast_tanh(score) * PI_F;
      __sincosf(0.5f*th, &sr[w], &cr[w]);
    }
  }

  // ---- value circuit: phi = U_v RX(x)|0>; RZ+CNOTs folded into expectations ----
  float o[8];
  {
    build_rx(st, cw, sw);
    sim_initqkv(st, ws + 64);      // v gates
    float p[16];
    #pragma unroll
    for (int i = 0; i < 16; i++) p[i] = st[i].x*st[i].x + st[i].y*st[i].y;
    // Z through CNOT chain -> Z-strings (diagonal; RZ phases cancel)
    constexpr int zm[4] = {8, 12, 14, 15};
    #pragma unroll
    for (int w = 0; w < 4; w++){
      float r = 0.f;
      #pragma unroll
      for (int i = 0; i < 16; i++)
        r += (__popc(i & zm[w]) & 1) ? -p[i] : p[i];
      o[w] = r;
    }
    // apply RZ phases: amp[i] *= prod_w e^{+-i th_w/2}
    c32 ph01[4], ph23[4];
    ph01[0] = { cr[0]*cr[1] - sr[0]*sr[1], -(cr[0]*sr[1] + sr[0]*cr[1]) };
    ph01[1] = { cr[0]*cr[1] + sr[0]*sr[1],   cr[0]*sr[1] - sr[0]*cr[1] };
    ph01[2] = { ph01[1].x, -ph01[1].y };
    ph01[3] = { ph01[0].x, -ph01[0].y };
    ph23[0] = { cr[2]*cr[3] - sr[2]*sr[3], -(cr[2]*sr[3] + sr[2]*cr[3]) };
    ph23[1] = { cr[2]*cr[3] + sr[2]*sr[3],   cr[2]*sr[3] - sr[2]*cr[3] };
    ph23[2] = { ph23[1].x, -ph23[1].y };
    ph23[3] = { ph23[0].x, -ph23[0].y };
    #pragma unroll
    for (int i = 0; i < 16; i++){
      c32 a = st[i], f = ph01[(i >> 2) & 3], g2 = ph23[i & 3];
      c32 b = { a.x*f.x - a.y*f.y, a.x*f.y + a.y*f.x };
      st[i] = { b.x*g2.x - b.y*g2.y, b.x*g2.y + b.y*g2.x };
    }
    // X through CNOT chain -> X-strings with masks {12,6,3,1}
    constexpr int xmk[4] = {12, 6, 3, 1};
    constexpr int hb[4]  = {8, 4, 2, 1};
    #pragma unroll
    for (int w = 0; w < 4; w++){
      float r = 0.f;
      #pragma unroll
      for (int i = 0; i < 16; i++){
        if (i & hb[w]) continue;
        const int j = i ^ xmk[w];
        r += st[i].x*st[j].x + st[i].y*st[j].y;
      }
      o[4 + w] = 2.f * r;
    }
  }

  // ---- LayerNorm(8) -> tanh-GELU -> head ----
  float mu = 0.f;
  #pragma unroll
  for (int j = 0; j < 8; j++) mu += o[j];
  mu *= 0.125f;
  float var = 0.f;
  #pragma unroll
  for (int j = 0; j < 8; j++){ float d = o[j] - mu; var += d*d; }
  var *= 0.125f;
  float inv = rsqrtf(var + 1e-5f);
  float h0 = head_b[0], h1 = head_b[1];
  #pragma unroll
  for (int j = 0; j < 8; j++){
    float y = (o[j] - mu) * inv * ln_w[j] + ln_b[j];
    float u = 0.7978845608f * (y + 0.044715f*y*y*y);
    float g = 0.5f * y * (1.f + fast_tanh(u));
    h0 += g * head_w[j];
    h1 += g * head_w[8 + j];
  }

  const int sid = base + t;
  if (sid < B){
    float2 r2; r2.x = h0; r2.y = h1;
    ((float2*)out)[sid] = r2;
  }
}

extern "C" void kernel_launch(void* const* d_in, const int* in_sizes, int n_in,
                              void* d_out, int out_size, void* d_ws, size_t ws_size,
                              hipStream_t stream) {
  const float* x1     = (const float*)d_in[0];
  const float* pre_w  = (const float*)d_in[1];
  const float* pre_b  = (const float*)d_in[2];
  const float* q_rot  = (const float*)d_in[3];
  const float* k_rot  = (const float*)d_in[4];
  const float* v_rot  = (const float*)d_in[5];
  const float* q_crx  = (const float*)d_in[6];
  const float* k_crx  = (const float*)d_in[7];
  const float* v_crx  = (const float*)d_in[8];
  const float* ln_w   = (const float*)d_in[9];
  const float* ln_b   = (const float*)d_in[10];
  const float* head_w = (const float*)d_in[11];
  const float* head_b = (const float*)d_in[12];
  float* out = (float*)d_out;
  float* ws  = (float*)d_ws;
  (void)ws_size; (void)n_in; (void)out_size;

  qc_setup<<<1, 64, 0, stream>>>(q_rot, k_rot, v_rot, q_crx, k_crx, v_crx, ws);

  const int B = in_sizes[0] / 96;
  const int nb = (B + 63) / 64;
  qc_main<<<nb, 64, 0, stream>>>(x1, pre_w, pre_b, ln_w, ln_b, head_w, head_b,
                                 (const float*)ws, out, B);
}

// Round 3
// 100.118 us; speedup vs baseline: 1.0599x; 1.0599x over previous
//
#include <hip/hip_runtime.h>
#include <math.h>

#define PI_F 3.14159265358979323846f

struct c32 { float x, y; };

// ---- 4-qubit state: 16 amps, wire w = bit (3-w) of index ----

// Rot gate in SU(2)-reduced form: matrix [[A, -conj(C)],[C, conj(A)]]
__device__ __forceinline__ void apply_rot_red(c32* s, const int w,
                                              float Ax, float Ay, float Cx, float Cy){
  const int m = 8 >> w;
  #pragma unroll
  for (int i = 0; i < 16; i++){
    if (i & m) continue;
    c32 a = s[i], b = s[i | m];
    s[i].x     = Ax*a.x - Ay*a.y - Cx*b.x - Cy*b.y;
    s[i].y     = Ax*a.y + Ay*a.x - Cx*b.y + Cy*b.x;
    s[i | m].x = Cx*a.x - Cy*a.y + Ax*b.x + Ay*b.y;
    s[i | m].y = Cx*a.y + Cy*a.x + Ax*b.y - Ay*b.x;
  }
}

// fused CRX(t) followed by CNOT on (control wa, target wb)
__device__ __forceinline__ void apply_crxnot(c32* s, const int wa, const int wb,
                                             float c, float sn){
  const int ma = 8 >> wa, mb = 8 >> wb;
  #pragma unroll
  for (int i = 0; i < 16; i++){
    if (!(i & ma) || (i & mb)) continue;
    c32 u = s[i], v = s[i | mb];
    s[i]      = { c*v.x + sn*u.y, c*v.y - sn*u.x };   // CNOT swap folded in
    s[i | mb] = { c*u.x + sn*v.y, c*u.y - sn*v.x };
  }
}

// gp: 8 gates x 8 floats {A.x,A.y,C.x,C.y,crx_c,crx_s,pad,pad} (LDS, wave-uniform reads)
__device__ __forceinline__ void sim_initqkv(c32* s, const float* gp){
  constexpr int pa[8] = {0,1,2,3,0,1,2,3};
  constexpr int pb[8] = {1,2,3,0,3,0,1,2};
  #pragma unroll
  for (int g = 0; g < 8; g++){
    const float* q = gp + 8*g;
    apply_rot_red(s, pa[g], q[0], q[1], q[2], q[3]);
    apply_crxnot(s, pa[g], pb[g], q[4], q[5]);
  }
}

// RX(x)|0000> is a product state: amp[i] = (prod of c/s) * (-i)^popcount(i)
__device__ __forceinline__ void build_rx(c32* s, const float* cw, const float* sw){
  float m01[4] = { cw[0]*cw[1], cw[0]*sw[1], sw[0]*cw[1], sw[0]*sw[1] };
  float m23[4] = { cw[2]*cw[3], cw[2]*sw[3], sw[2]*cw[3], sw[2]*sw[3] };
  #pragma unroll
  for (int i = 0; i < 16; i++){
    float mag = m01[(i >> 2) & 3] * m23[i & 3];
    const int pc = __popc(i) & 3;
    s[i] = (pc == 0) ? c32{ mag, 0.f } :
           (pc == 1) ? c32{ 0.f, -mag } :
           (pc == 2) ? c32{ -mag, 0.f } : c32{ 0.f, mag };
  }
}

__device__ __forceinline__ float fast_tanh(float x){
  float e = __expf(2.f * x);
  return 1.f - 2.f * __builtin_amdgcn_rcpf(e + 1.f);
}

#define LDS_STRIDE 97   // 97 % 32 == 1 -> only 2-way bank aliasing on row reads (free)

// Single fused kernel: per-block cooperative setup (threads 0-23, one gate each)
// + per-thread sample pipeline. No second launch, no d_ws round-trip.
__global__ __launch_bounds__(64, 1) void qc_main(
    const float* __restrict__ x1,
    const float* __restrict__ pre_w, const float* __restrict__ pre_b,
    const float* __restrict__ q_rot, const float* __restrict__ k_rot, const float* __restrict__ v_rot,
    const float* __restrict__ q_crx, const float* __restrict__ k_crx, const float* __restrict__ v_crx,
    const float* __restrict__ ln_w, const float* __restrict__ ln_b,
    const float* __restrict__ head_w, const float* __restrict__ head_b,
    float* __restrict__ out, int B){

  __shared__ float xs[64 * LDS_STRIDE];
  __shared__ float gates[3 * 64];      // [q | k | v], 8 gates x 8 floats each
  const int t = threadIdx.x;
  const int base = blockIdx.x * 64;

  // ---- cooperative setup: thread t<24 computes gate (t>>3 circuit, t&7 index) ----
  if (t < 24){
    const int grp = t >> 3, g = t & 7;
    const float* rotp = grp == 0 ? q_rot : (grp == 1 ? k_rot : v_rot);
    const float* crxp = grp == 0 ? q_crx : (grp == 1 ? k_crx : v_crx);
    float phi = rotp[3*g], th = rotp[3*g+1], om = rotp[3*g+2];
    float c, s, ca, sa, cb, sb;
    __sincosf(0.5f*th,       &s,  &c);
    __sincosf(0.5f*(phi+om), &sa, &ca);
    __sincosf(0.5f*(phi-om), &sb, &cb);
    float cc, cs; __sincosf(0.5f*crxp[g], &cs, &cc);
    float* dst = &gates[64*grp + 8*g];
    dst[0] = c*ca; dst[1] = -c*sa; dst[2] = s*cb; dst[3] = -s*sb;
    dst[4] = cc;   dst[5] = cs;
  }

  // ---- stage 64x96 slice of x1 into LDS (coalesced float4) ----
  {
    int rem = B - base; if (rem > 64) rem = 64;
    const int nf4 = rem * 24;
    const float4* src = (const float4*)(x1 + (long)base * 96);
    #pragma unroll
    for (int k = 0; k < 24; k++){
      int g = t + 64*k;
      if (g < nf4){
        float4 v = src[g];
        int f = 4*g;
        int r = f / 96, cidx = f - 96*r;
        float* d = &xs[r*LDS_STRIDE + cidx];
        d[0]=v.x; d[1]=v.y; d[2]=v.z; d[3]=v.w;
      }
    }
  }
  __syncthreads();

  // ---- k-circuit expX constants (batch-uniform; recompute per thread from LDS) ----
  float cxk[4];
  {
    c32 ks[16];
    #pragma unroll
    for (int i = 0; i < 16; i++) ks[i] = { 0.f, 0.f };
    ks[0] = { 1.f, 0.f };
    sim_initqkv(ks, &gates[64]);
    #pragma unroll
    for (int w = 0; w < 4; w++){
      const int m = 8 >> w;
      float r = 0.f;
      #pragma unroll
      for (int i = 0; i < 16; i++){
        if (i & m) continue;
        r += ks[i].x*ks[i|m].x + ks[i].y*ks[i|m].y;
      }
      cxk[w] = 2.f * r;
    }
  }

  // ---- x = row @ pre_w.T + pre_b (pre_w uniform -> scalar loads) ----
  float xw[4];
  {
    float a0 = pre_b[0], a1 = pre_b[1], a2 = pre_b[2], a3 = pre_b[3];
    const float* row = &xs[t * LDS_STRIDE];
    #pragma unroll
    for (int j = 0; j < 96; j++){
      float v = row[j];
      a0 += v * pre_w[j];
      a1 += v * pre_w[96  + j];
      a2 += v * pre_w[192 + j];
      a3 += v * pre_w[288 + j];
    }
    xw[0]=a0; xw[1]=a1; xw[2]=a2; xw[3]=a3;
  }

  float cw[4], sw[4];
  #pragma unroll
  for (int w = 0; w < 4; w++) __sincosf(0.5f*xw[w], &sw[w], &cw[w]);

  c32 st[16];

  // ---- q-circuit: phi = U_q RX(x)|0>; post-RX layer folded into expectations ----
  float cr[4], sr[4];   // half-angle cos/sin of RZ angles for v-circuit
  {
    build_rx(st, cw, sw);
    sim_initqkv(st, &gates[0]);    // q gates
    float p[16];
    #pragma unroll
    for (int i = 0; i < 16; i++) p[i] = st[i].x*st[i].x + st[i].y*st[i].y;
    #pragma unroll
    for (int w = 0; w < 4; w++){
      const int m = 8 >> w;
      float sz = 0.f, sx = 0.f, sy = 0.f;
      #pragma unroll
      for (int i = 0; i < 16; i++) sz += (i & m) ? -p[i] : p[i];
      #pragma unroll
      for (int i = 0; i < 16; i++){
        if (i & m) continue;
        c32 a = st[i], b = st[i|m];
        sx += a.x*b.x + a.y*b.y;
        sy += a.x*b.y - a.y*b.x;
      }
      // RX(theta)^dag Z RX(theta) = cos(th) Z + sin(th) Y ; X invariant under RX
      float cth = 1.f - 2.f*sw[w]*sw[w];
      float sth = 2.f*sw[w]*cw[w];
      float z   = cth*sz + sth*(2.f*sy);
      float xm  = (2.f*sx) * cxk[w];
      float score = sqrtf(z*z + xm*xm);
      float th = fast_tanh(score) * PI_F;
      __sincosf(0.5f*th, &sr[w], &cr[w]);
    }
  }

  // ---- value circuit: phi = U_v RX(x)|0>; RZ+CNOTs folded into expectations ----
  float o[8];
  {
    build_rx(st, cw, sw);
    sim_initqkv(st, &gates[128]);  // v gates
    float p[16];
    #pragma unroll
    for (int i = 0; i < 16; i++) p[i] = st[i].x*st[i].x + st[i].y*st[i].y;
    // Z through CNOT chain -> Z-strings (diagonal; RZ phases cancel)
    constexpr int zm[4] = {8, 12, 14, 15};
    #pragma unroll
    for (int w = 0; w < 4; w++){
      float r = 0.f;
      #pragma unroll
      for (int i = 0; i < 16; i++)
        r += (__popc(i & zm[w]) & 1) ? -p[i] : p[i];
      o[w] = r;
    }
    // apply RZ phases: amp[i] *= prod_w e^{+-i th_w/2}
    c32 ph01[4], ph23[4];
    ph01[0] = { cr[0]*cr[1] - sr[0]*sr[1], -(cr[0]*sr[1] + sr[0]*cr[1]) };
    ph01[1] = { cr[0]*cr[1] + sr[0]*sr[1],   cr[0]*sr[1] - sr[0]*cr[1] };
    ph01[2] = { ph01[1].x, -ph01[1].y };
    ph01[3] = { ph01[0].x, -ph01[0].y };
    ph23[0] = { cr[2]*cr[3] - sr[2]*sr[3], -(cr[2]*sr[3] + sr[2]*cr[3]) };
    ph23[1] = { cr[2]*cr[3] + sr[2]*sr[3],   cr[2]*sr[3] - sr[2]*cr[3] };
    ph23[2] = { ph23[1].x, -ph23[1].y };
    ph23[3] = { ph23[0].x, -ph23[0].y };
    #pragma unroll
    for (int i = 0; i < 16; i++){
      c32 a = st[i], f = ph01[(i >> 2) & 3], g2 = ph23[i & 3];
      c32 b = { a.x*f.x - a.y*f.y, a.x*f.y + a.y*f.x };
      st[i] = { b.x*g2.x - b.y*g2.y, b.x*g2.y + b.y*g2.x };
    }
    // X through CNOT chain -> X-strings with masks {12,6,3,1}
    constexpr int xmk[4] = {12, 6, 3, 1};
    constexpr int hb[4]  = {8, 4, 2, 1};
    #pragma unroll
    for (int w = 0; w < 4; w++){
      float r = 0.f;
      #pragma unroll
      for (int i = 0; i < 16; i++){
        if (i & hb[w]) continue;
        const int j = i ^ xmk[w];
        r += st[i].x*st[j].x + st[i].y*st[j].y;
      }
      o[4 + w] = 2.f * r;
    }
  }

  // ---- LayerNorm(8) -> tanh-GELU -> head ----
  float mu = 0.f;
  #pragma unroll
  for (int j = 0; j < 8; j++) mu += o[j];
  mu *= 0.125f;
  float var = 0.f;
  #pragma unroll
  for (int j = 0; j < 8; j++){ float d = o[j] - mu; var += d*d; }
  var *= 0.125f;
  float inv = rsqrtf(var + 1e-5f);
  float h0 = head_b[0], h1 = head_b[1];
  #pragma unroll
  for (int j = 0; j < 8; j++){
    float y = (o[j] - mu) * inv * ln_w[j] + ln_b[j];
    float u = 0.7978845608f * (y + 0.044715f*y*y*y);
    float g = 0.5f * y * (1.f + fast_tanh(u));
    h0 += g * head_w[j];
    h1 += g * head_w[8 + j];
  }

  const int sid = base + t;
  if (sid < B){
    float2 r2; r2.x = h0; r2.y = h1;
    ((float2*)out)[sid] = r2;
  }
}

extern "C" void kernel_launch(void* const* d_in, const int* in_sizes, int n_in,
                              void* d_out, int out_size, void* d_ws, size_t ws_size,
                              hipStream_t stream) {
  const float* x1     = (const float*)d_in[0];
  const float* pre_w  = (const float*)d_in[1];
  const float* pre_b  = (const float*)d_in[2];
  const float* q_rot  = (const float*)d_in[3];
  const float* k_rot  = (const float*)d_in[4];
  const float* v_rot  = (const float*)d_in[5];
  const float* q_crx  = (const float*)d_in[6];
  const float* k_crx  = (const float*)d_in[7];
  const float* v_crx  = (const float*)d_in[8];
  const float* ln_w   = (const float*)d_in[9];
  const float* ln_b   = (const float*)d_in[10];
  const float* head_w = (const float*)d_in[11];
  const float* head_b = (const float*)d_in[12];
  float* out = (float*)d_out;
  (void)d_ws; (void)ws_size; (void)n_in; (void)out_size;

  const int B = in_sizes[0] / 96;
  const int nb = (B + 63) / 64;
  qc_main<<<nb, 64, 0, stream>>>(x1, pre_w, pre_b,
                                 q_rot, k_rot, v_rot,
                                 q_crx, k_crx, v_crx,
                                 ln_w, ln_b, head_w, head_b,
                                 out, B);
}